// Round 8
// baseline (4146.548 us; speedup 1.0000x reference)
//
#include <hip/hip_runtime.h>
#include <math.h>

#define NFFT   1024
#define NH     512
#define HOP    64
#define NMELS  80
#define NFR    512
#define NBINS  513
#define NITER  300
#define SIGLEN 33728
#define NT     256
#define NB     512

// ---- workspace layout (4B units) ----
#define TBL_WIN  0          // win[1024]
#define TBL_TWR  1024       // twr[256]
#define TBL_TWI  1280       // twi[256]
#define TBL_W1R  1536       // w1r[513]
#define TBL_W1I  2056       // w1i[513]
#define BAR_SLOT 2624       // 512 int slots
#define BAR_GEN  3200       // generation word
#define OFF_MAG  4096       // mag[512*513]
#define OFF_IWS  266752     // iws[33728]
#define OFF_F    300480     // F[512*1024]
#define OFF_X    824768     // x[33792]

typedef unsigned long long u64;
typedef unsigned int u32;

// ---- coherent (agent-scope sc1, L3-point) accessors ----
__device__ __forceinline__ float2 coh_load2(const float* p) {
    u64 a = __hip_atomic_load((const u64*)p, __ATOMIC_RELAXED, __HIP_MEMORY_SCOPE_AGENT);
    float2 f;
    __builtin_memcpy(&f, &a, 8);
    return f;
}
__device__ __forceinline__ void coh_store2(float* p, float2 v) {
    u64 a;
    __builtin_memcpy(&a, &v, 8);
    __hip_atomic_store((u64*)p, a, __ATOMIC_RELAXED, __HIP_MEMORY_SCOPE_AGENT);
}
__device__ __forceinline__ float coh_load1(const float* p) {
    u32 a = __hip_atomic_load((const u32*)p, __ATOMIC_RELAXED, __HIP_MEMORY_SCOPE_AGENT);
    float f;
    __builtin_memcpy(&f, &a, 4);
    return f;
}
__device__ __forceinline__ void coh_store1(float* p, float v) {
    u32 a;
    __builtin_memcpy(&a, &v, 4);
    __hip_atomic_store((u32*)p, a, __ATOMIC_RELAXED, __HIP_MEMORY_SCOPE_AGENT);
}

// ---- radix-4 Stockham stage (verified), caller guards tid<128 ----
template<int P, int SH, bool INV>
__device__ __forceinline__ void r4b(const float* __restrict__ sR, const float* __restrict__ sI,
                                    float* __restrict__ dR, float* __restrict__ dI,
                                    const float* twr, const float* twi, int j) {
    int k  = j & (P - 1);
    int d0 = ((j - k) << 2) + k;
    float x0r = sR[j],       x0i = sI[j];
    float x1r = sR[j + 128], x1i = sI[j + 128];
    float x2r = sR[j + 256], x2i = sI[j + 256];
    float x3r = sR[j + 384], x3i = sI[j + 384];
    int tb = k << SH;
    float c1 = twr[tb], s1 = twi[tb];
    if (INV) s1 = -s1;
    float c2 = c1 * c1 - s1 * s1, s2 = 2.f * c1 * s1;
    float c3 = c1 * c2 - s1 * s2, s3 = c1 * s2 + s1 * c2;
    float a1r = x1r * c1 - x1i * s1, a1i = x1r * s1 + x1i * c1;
    float a2r = x2r * c2 - x2i * s2, a2i = x2r * s2 + x2i * c2;
    float a3r = x3r * c3 - x3i * s3, a3i = x3r * s3 + x3i * c3;
    float t0r = x0r + a2r, t0i = x0i + a2i;
    float t1r = x0r - a2r, t1i = x0i - a2i;
    float t2r = a1r + a3r, t2i = a1i + a3i;
    float t3r = a1r - a3r, t3i = a1i - a3i;
    float i3r = INV ? -t3i : t3i;
    float i3i = INV ?  t3r : -t3r;
    dR[d0]         = t0r + t2r;  dI[d0]         = t0i + t2i;
    dR[d0 + P]     = t1r + i3r;  dI[d0 + P]     = t1i + i3i;
    dR[d0 + 2 * P] = t0r - t2r;  dI[d0 + 2 * P] = t0i - t2i;
    dR[d0 + 3 * P] = t1r - i3r;  dI[d0 + 3 * P] = t1i - i3i;
}

// ================= k_init (round-7 verified, unchanged) ======================
struct __align__(16) SMemI {
    float xb[NFFT];
    float C0r[NH], C0i[NH];
    float C1r[NH], C1i[NH];
    float win[NFFT];
    float twr[256], twi[256];
    float mag[516];
};

extern "C" __global__ __launch_bounds__(NT)
void k_init(const float* __restrict__ mel,
            const float* __restrict__ invmel,
            float* __restrict__ ws) {
    __shared__ SMemI sm;
    const int tid = threadIdx.x;
    const int t   = blockIdx.x;

    for (int n = tid; n < NFFT; n += NT) {
        double a = (2.0 * 3.14159265358979323846) * (double)n / 1024.0;
        sm.win[n] = (float)(0.5 - 0.5 * cos(a));
    }
    for (int j = tid; j < 256; j += NT) {
        double a = (2.0 * 3.14159265358979323846) * (double)j / 512.0;
        sm.twr[j] = (float)cos(a);
        sm.twi[j] = (float)(-sin(a));
    }
    __syncthreads();
    if (t == 0) {
        for (int n = tid; n < NFFT; n += NT) ws[TBL_WIN + n] = sm.win[n];
        for (int j = tid; j < 256; j += NT) {
            ws[TBL_TWR + j] = sm.twr[j];
            ws[TBL_TWI + j] = sm.twi[j];
        }
        for (int k = tid; k < NBINS; k += NT) {
            double a = (2.0 * 3.14159265358979323846) * (double)k / 1024.0;
            ws[TBL_W1R + k] = (float)cos(a);
            ws[TBL_W1I + k] = (float)sin(a);
        }
        ((int*)ws)[BAR_SLOT + tid]       = 0;
        ((int*)ws)[BAR_SLOT + 256 + tid] = 0;
        if (tid == 0) ((int*)ws)[BAR_GEN] = 0;
    }

    for (int p = t * NT + tid; p < SIGLEN; p += NFR * NT) {
        int tq = p >> 6, io = p & 63;
        float s = 0.f;
#pragma unroll
        for (int m = 0; m < 16; ++m) {
            int tp = tq - m;
            if (tp >= 0 && tp < NFR) {
                float w = sm.win[io + (m << 6)];
                s += w * w;
            }
        }
        ws[OFF_IWS + p] = (s > 1e-11f) ? (1.0f / s) : 1.0f;
    }

    if (tid < NMELS) sm.xb[tid] = exp10f(mel[tid * NFR + t]);
    __syncthreads();
    for (int k = tid; k < NBINS; k += NT) {
        const float* row = invmel + k * NMELS;
        float s = 0.f;
#pragma unroll 8
        for (int j = 0; j < NMELS; ++j) s += row[j] * sm.xb[j];
        ws[OFF_MAG + t * NBINS + k] = s;
        sm.mag[k] = s;
    }
    __syncthreads();

    for (int k = tid; k < NH; k += NT) {
        float xr = sm.mag[k], yr = sm.mag[512 - k];
        double a = (2.0 * 3.14159265358979323846) * (double)k / 1024.0;
        float c = (float)cos(a), s = (float)sin(a);
        float dr = xr - yr;
        sm.C1r[k] = ((xr + yr) - s * dr) * (1.0f / 1024.0f);
        sm.C1i[k] = (c * dr) * (1.0f / 1024.0f);
    }
    __syncthreads();
    if (tid < 128) {
        float x0r = sm.C1r[tid],       x0i = sm.C1i[tid];
        float x1r = sm.C1r[tid + 128], x1i = sm.C1i[tid + 128];
        float x2r = sm.C1r[tid + 256], x2i = sm.C1i[tid + 256];
        float x3r = sm.C1r[tid + 384], x3i = sm.C1i[tid + 384];
        float t0r = x0r + x2r, t0i = x0i + x2i;
        float t1r = x0r - x2r, t1i = x0i - x2i;
        float t2r = x1r + x3r, t2i = x1i + x3i;
        float t3r = x1r - x3r, t3i = x1i - x3i;
        float4 vr = make_float4(t0r + t2r, t1r - t3i, t0r - t2r, t1r + t3i);
        float4 vi = make_float4(t0i + t2i, t1i + t3r, t0i - t2i, t1i - t3r);
        ((float4*)sm.C0r)[tid] = vr;
        ((float4*)sm.C0i)[tid] = vi;
    }
    __syncthreads();
    if (tid < 128) r4b<4, 5, true>(sm.C0r, sm.C0i, sm.C1r, sm.C1i, sm.twr, sm.twi, tid);
    __syncthreads();
    if (tid < 128) r4b<16, 3, true>(sm.C1r, sm.C1i, sm.C0r, sm.C0i, sm.twr, sm.twi, tid);
    __syncthreads();
    if (tid < 128) r4b<64, 1, true>(sm.C0r, sm.C0i, sm.C1r, sm.C1i, sm.twr, sm.twi, tid);
    __syncthreads();
    {
        float c = sm.twr[tid], s = -sm.twi[tid];
        float x0r = sm.C1r[tid], x0i = sm.C1i[tid];
        float x1r = sm.C1r[tid + 256], x1i = sm.C1i[tid + 256];
        float ar = x1r * c - x1i * s, ai = x1r * s + x1i * c;
        sm.C0r[tid]       = x0r + ar;  sm.C0i[tid]       = x0i + ai;
        sm.C0r[tid + 256] = x0r - ar;  sm.C0i[tid + 256] = x0i - ai;
    }
    __syncthreads();

    float4 w4 = ((float4*)sm.win)[tid];
    float4 o;
    o.x = w4.x * sm.C0r[2 * tid];
    o.y = w4.y * sm.C0i[2 * tid];
    o.z = w4.z * sm.C0r[2 * tid + 1];
    o.w = w4.w * sm.C0i[2 * tid + 1];
    *(float4*)&ws[OFF_F + (t << 10) + (tid << 2)] = o;
}

// ============== persistent Griffin-Lim: global barrier, fused ends ==========
struct __align__(16) SM1 {
    float C0r[NH], C0i[NH];
    float C1r[NH], C1i[NH];
    float twr[256], twi[256];
};

// two-hop global barrier (round-7 proven structure); block0 gather by 1 wave.
__device__ __forceinline__ void gbar(int* bar, int t, int tid, int bc) {
    __syncthreads();   // block work done; vmcnt drained -> sc1 stores at L3
    if (tid == 0)
        __hip_atomic_store(bar + BAR_SLOT + t, bc,
                           __ATOMIC_RELAXED, __HIP_MEMORY_SCOPE_AGENT);
    if (t == 0 && tid < 64) {
        // one wave gathers all 512 slots (8 per lane); SIMD reconvergence
        // guarantees all lanes done before lane 0 releases gen.
#pragma unroll
        for (int q = 0; q < 8; ++q) {
            const int* f = bar + BAR_SLOT + (q << 6) + tid;
            while (__hip_atomic_load(f, __ATOMIC_RELAXED, __HIP_MEMORY_SCOPE_AGENT) < bc)
                __builtin_amdgcn_s_sleep(1);
        }
        if (tid == 0)
            __hip_atomic_store(bar + BAR_GEN, bc,
                               __ATOMIC_RELAXED, __HIP_MEMORY_SCOPE_AGENT);
    }
    if (tid == 0) {
        while (__hip_atomic_load(bar + BAR_GEN,
                                 __ATOMIC_RELAXED, __HIP_MEMORY_SCOPE_AGENT) < bc)
            __builtin_amdgcn_s_sleep(2);
    }
    __syncthreads();
}

extern "C" __global__ __launch_bounds__(NT)
void k_persist(float* __restrict__ ws, float* __restrict__ out) {
    __shared__ SM1 sm;
    const int tid = threadIdx.x;
    const int t   = blockIdx.x;       // frame owned
    const int j2  = 512 - tid;

    const float* tbl  = ws;
    const float* magg = ws + OFF_MAG;
    const float* iws  = ws + OFF_IWS;
    float* F  = ws + OFF_F;
    float* X  = ws + OFF_X;
    int*   bar = (int*)ws;

    // ---- one-time staging ----
    if (tid < 64)       ((float4*)sm.twr)[tid]      = ((const float4*)(tbl + TBL_TWR))[tid];
    else if (tid < 128) ((float4*)sm.twi)[tid - 64] = ((const float4*)(tbl + TBL_TWI))[tid - 64];

    // window register pairs
    const float2* winp = (const float2*)(tbl + TBL_WIN);
    float2 wa = winp[tid];         // win[2tid], win[2tid+1]
    float2 wb = winp[tid + 256];   // win[2tid+512], win[2tid+513]
    float2 wz0 = make_float2(0.f, 0.f), wz1 = wz0, wz2 = wz0, wz3 = wz0;
    if (tid < 128) {
        wz0 = winp[tid];           // win[2tid], +1
        wz1 = winp[tid + 128];     // win[2tid+256], +1
        wz2 = winp[tid + 256];     // win[2tid+512], +1
        wz3 = winp[tid + 384];     // win[2tid+768], +1
    }

    float m_a, m_b, m_ny = 0.f, w1r_a, w1i_a, w1r_b, w1i_b;
    {
        const int s0 = t * NBINS;
        if (tid == 0) {
            m_a = magg[s0]; m_ny = magg[s0 + 512]; m_b = magg[s0 + 256];
            w1r_a = 1.f; w1i_a = 0.f; w1r_b = 0.f; w1i_b = 1.f;
        } else {
            m_a = magg[s0 + tid]; m_b = magg[s0 + j2];
            w1r_a = tbl[TBL_W1R + tid]; w1i_a = tbl[TBL_W1I + tid];
            w1r_b = tbl[TBL_W1R + j2];  w1i_b = tbl[TBL_W1I + j2];
        }
    }
    // segment ownership: seg t (lanes 0..63); blocks >=497 also seg t+15 (lanes 64..127)
    const bool extra = (t >= 497);
    int gseg = -1;
    if (tid < 64) gseg = t;
    else if (tid < 128 && extra) gseg = t + 15;
    const int u = tid & 63;
    float iwreg = 0.f;
    if (gseg >= 0) iwreg = iws[(gseg << 6) + u];

    // ---- prologue: x^0 segment(s) from k_init frames ----
    if (gseg >= 0) {
        float acc = 0.f;
#pragma unroll
        for (int m = 0; m < 16; ++m) {
            int tp = gseg - m;
            if (tp >= 0 && tp < NFR)
                acc += coh_load1(&F[(tp << 10) + u + (m << 6)]);
        }
        coh_store1(&X[(gseg << 6) + u], acc * iwreg);
    }
    gbar(bar, t, tid, 1);

    int bc = 2;
#pragma unroll 1
    for (int it = 1; it <= NITER; ++it) {
        // ===== phase A =====
        // fused: coherent X load + window + fwd radix-4 stage0 -> C0
        if (tid < 128) {
            const float* xp = X + (t << 6) + (tid << 1);
            float2 z0 = coh_load2(xp);
            float2 z1 = coh_load2(xp + 256);
            float2 z2 = coh_load2(xp + 512);
            float2 z3 = coh_load2(xp + 768);
            float x0r = z0.x * wz0.x, x0i = z0.y * wz0.y;
            float x1r = z1.x * wz1.x, x1i = z1.y * wz1.y;
            float x2r = z2.x * wz2.x, x2i = z2.y * wz2.y;
            float x3r = z3.x * wz3.x, x3i = z3.y * wz3.y;
            float t0r = x0r + x2r, t0i = x0i + x2i;
            float t1r = x0r - x2r, t1i = x0i - x2i;
            float t2r = x1r + x3r, t2i = x1i + x3i;
            float t3r = x1r - x3r, t3i = x1i - x3i;
            float4 vr = make_float4(t0r + t2r, t1r + t3i, t0r - t2r, t1r - t3i);
            float4 vi = make_float4(t0i + t2i, t1i - t3r, t0i - t2i, t1i + t3r);
            ((float4*)sm.C0r)[tid] = vr;
            ((float4*)sm.C0i)[tid] = vi;
        }
        __syncthreads();
        if (tid < 128) r4b<4, 5, false>(sm.C0r, sm.C0i, sm.C1r, sm.C1i, sm.twr, sm.twi, tid);
        __syncthreads();
        if (tid < 128) r4b<16, 3, false>(sm.C1r, sm.C1i, sm.C0r, sm.C0i, sm.twr, sm.twi, tid);
        __syncthreads();
        if (tid < 128) r4b<64, 1, false>(sm.C0r, sm.C0i, sm.C1r, sm.C1i, sm.twr, sm.twi, tid);
        __syncthreads();
        {   // final radix-2 fwd: C1 -> C0
            float c = sm.twr[tid], s = sm.twi[tid];
            float x0r = sm.C1r[tid], x0i = sm.C1i[tid];
            float x1r = sm.C1r[tid + 256], x1i = sm.C1i[tid + 256];
            float ar = x1r * c - x1i * s, ai = x1r * s + x1i * c;
            sm.C0r[tid]       = x0r + ar;  sm.C0i[tid]       = x0i + ai;
            sm.C0r[tid + 256] = x0r - ar;  sm.C0i[tid + 256] = x0i - ai;
        }
        __syncthreads();

        // fused unpack + phase projection + iFFT prep: C0 -> C1
        if (tid == 0) {
            float zr = sm.C0r[0], zi = sm.C0i[0];
            float e0 = zr + zi;
            float e5 = zr - zi;
            float X0 = m_a  * e0 / fmaxf(1e-8f, fabsf(e0));
            float X5 = m_ny * e5 / fmaxf(1e-8f, fabsf(e5));
            sm.C1r[0] = (X0 + X5) * (1.0f / 1024.0f);
            sm.C1i[0] = (X0 - X5) * (1.0f / 1024.0f);
            float z6r = sm.C0r[256], z6i = sm.C0i[256];
            float sc6 = m_b / fmaxf(1e-8f, sqrtf(z6r * z6r + z6i * z6i));
            float X6r = z6r * sc6, X6i = -z6i * sc6;
            sm.C1r[256] = X6r * (2.0f / 1024.0f);
            sm.C1i[256] = -X6i * (2.0f / 1024.0f);
        } else {
            float zr = sm.C0r[tid], zi = sm.C0i[tid];
            float ur = sm.C0r[j2],  ui = sm.C0i[j2];
            float er = 0.5f * (zr + ur), ei = 0.5f * (zi - ui);
            float dr = zr - ur,          di = zi + ui;
            float odr = 0.5f * di, odi = -0.5f * dr;
            float e1r = er + w1r_a * odr + w1i_a * odi;
            float e1i = ei + w1r_a * odi - w1i_a * odr;
            float e2r =  er + w1r_b * odr - w1i_b * odi;
            float e2i = -ei - w1r_b * odi - w1i_b * odr;
            float sc1 = m_a / fmaxf(1e-8f, sqrtf(e1r * e1r + e1i * e1i));
            float sc2 = m_b / fmaxf(1e-8f, sqrtf(e2r * e2r + e2i * e2i));
            float X1r = e1r * sc1, X1i = e1i * sc1;
            float X2r = e2r * sc2, X2i = e2i * sc2;
            float Er = X1r + X2r, Ei = X1i - X2i;
            float Dr = X1r - X2r, Di = X1i + X2i;
            float wdr = w1r_a * Dr - w1i_a * Di, wdi = w1r_a * Di + w1i_a * Dr;
            sm.C1r[tid] = (Er - wdi) * (1.0f / 1024.0f);
            sm.C1i[tid] = (Ei + wdr) * (1.0f / 1024.0f);
            float wdr2 = -w1r_b * Dr - w1i_b * Di, wdi2 = w1r_b * Di - w1i_b * Dr;
            sm.C1r[j2] = (Er - wdi2) * (1.0f / 1024.0f);
            sm.C1i[j2] = (-Ei + wdr2) * (1.0f / 1024.0f);
        }
        __syncthreads();

        // inverse FFT: C1 -> ... -> C1 (last r4 writes C1)
        if (tid < 128) {
            float x0r = sm.C1r[tid],       x0i = sm.C1i[tid];
            float x1r = sm.C1r[tid + 128], x1i = sm.C1i[tid + 128];
            float x2r = sm.C1r[tid + 256], x2i = sm.C1i[tid + 256];
            float x3r = sm.C1r[tid + 384], x3i = sm.C1i[tid + 384];
            float t0r = x0r + x2r, t0i = x0i + x2i;
            float t1r = x0r - x2r, t1i = x0i - x2i;
            float t2r = x1r + x3r, t2i = x1i + x3i;
            float t3r = x1r - x3r, t3i = x1i - x3i;
            float4 vr = make_float4(t0r + t2r, t1r - t3i, t0r - t2r, t1r + t3i);
            float4 vi = make_float4(t0i + t2i, t1i + t3r, t0i - t2i, t1i - t3r);
            ((float4*)sm.C0r)[tid] = vr;
            ((float4*)sm.C0i)[tid] = vi;
        }
        __syncthreads();
        if (tid < 128) r4b<4, 5, true>(sm.C0r, sm.C0i, sm.C1r, sm.C1i, sm.twr, sm.twi, tid);
        __syncthreads();
        if (tid < 128) r4b<16, 3, true>(sm.C1r, sm.C1i, sm.C0r, sm.C0i, sm.twr, sm.twi, tid);
        __syncthreads();
        if (tid < 128) r4b<64, 1, true>(sm.C0r, sm.C0i, sm.C1r, sm.C1i, sm.twr, sm.twi, tid);
        __syncthreads();
        {   // fused inv final radix-2 + window + coherent frame store
            float c = sm.twr[tid], s = -sm.twi[tid];
            float x0r = sm.C1r[tid], x0i = sm.C1i[tid];
            float x1r = sm.C1r[tid + 256], x1i = sm.C1i[tid + 256];
            float ar = x1r * c - x1i * s, ai = x1r * s + x1i * c;
            float y0r = x0r + ar, y0i = x0i + ai;   // frame[2tid], frame[2tid+1]
            float y1r = x0r - ar, y1i = x0i - ai;   // frame[2tid+512], frame[2tid+513]
            coh_store2(&F[(t << 10) + (tid << 1)],
                       make_float2(wa.x * y0r, wa.y * y0i));
            coh_store2(&F[(t << 10) + 512 + (tid << 1)],
                       make_float2(wb.x * y1r, wb.y * y1i));
        }
        gbar(bar, t, tid, bc++);   // F^{it} complete everywhere

        // ===== phase B: OLA own segment(s) =====
        if (gseg >= 0) {
            float acc = 0.f;
#pragma unroll
            for (int m = 0; m < 16; ++m) {
                int tp = gseg - m;
                if (tp >= 0 && tp < NFR)
                    acc += coh_load1(&F[(tp << 10) + u + (m << 6)]);
            }
            float val = acc * iwreg;
            if (it < NITER) coh_store1(&X[(gseg << 6) + u], val);
            else            out[(gseg << 6) + u] = val;
        }
        if (it < NITER)
            gbar(bar, t, tid, bc++);   // x^{it} complete everywhere
    }
}

extern "C" void kernel_launch(void* const* d_in, const int* in_sizes, int n_in,
                              void* d_out, int out_size, void* d_ws, size_t ws_size,
                              hipStream_t stream) {
    const float* mel    = (const float*)d_in[0];
    const float* invmel = (const float*)d_in[1];
    float* out = (float*)d_out;
    float* ws  = (float*)d_ws;

    k_init<<<NFR, NT, 0, stream>>>(mel, invmel, ws);
    k_persist<<<NB, NT, 0, stream>>>(ws, out);
}

// Round 9
// 3258.710 us; speedup vs baseline: 1.2725x; 1.2725x over previous
//
#include <hip/hip_runtime.h>
#include <math.h>

#define NFFT   1024
#define NH     512
#define HOP    64
#define NMELS  80
#define NFR    512
#define NBINS  513
#define NITER  300
#define SIGLEN 33728
#define NT     256
#define NB     512

// ---- workspace layout (4B units) ----
#define TBL_WIN  0          // win[1024]
#define TBL_TWR  1024       // twr[256]
#define TBL_TWI  1280       // twi[256]
#define TBL_W1R  1536       // w1r[513]
#define TBL_W1I  2056       // w1i[513]
#define BAR_SLOT 2624       // 512 int slots
#define BAR_GEN  3200       // generation word
#define OFF_MAG  4096       // mag[512*513]
#define OFF_IWS  266752     // iws[33728]
#define OFF_F    300480     // F[512*1024]
#define OFF_X    824768     // x[33792]

typedef unsigned long long u64;
typedef unsigned int u32;

// ---- coherent (agent-scope sc1, L3-point) accessors ----
__device__ __forceinline__ float2 coh_load2(const float* p) {
    u64 a = __hip_atomic_load((const u64*)p, __ATOMIC_RELAXED, __HIP_MEMORY_SCOPE_AGENT);
    float2 f;
    __builtin_memcpy(&f, &a, 8);
    return f;
}
__device__ __forceinline__ void coh_store2(float* p, float2 v) {
    u64 a;
    __builtin_memcpy(&a, &v, 8);
    __hip_atomic_store((u64*)p, a, __ATOMIC_RELAXED, __HIP_MEMORY_SCOPE_AGENT);
}
__device__ __forceinline__ float coh_load1(const float* p) {
    u32 a = __hip_atomic_load((const u32*)p, __ATOMIC_RELAXED, __HIP_MEMORY_SCOPE_AGENT);
    float f;
    __builtin_memcpy(&f, &a, 4);
    return f;
}
__device__ __forceinline__ void coh_store1(float* p, float v) {
    u32 a;
    __builtin_memcpy(&a, &v, 4);
    __hip_atomic_store((u32*)p, a, __ATOMIC_RELAXED, __HIP_MEMORY_SCOPE_AGENT);
}

// ---- radix-4 Stockham stage (verified), caller guards tid<128 ----
template<int P, int SH, bool INV>
__device__ __forceinline__ void r4b(const float* __restrict__ sR, const float* __restrict__ sI,
                                    float* __restrict__ dR, float* __restrict__ dI,
                                    const float* twr, const float* twi, int j) {
    int k  = j & (P - 1);
    int d0 = ((j - k) << 2) + k;
    float x0r = sR[j],       x0i = sI[j];
    float x1r = sR[j + 128], x1i = sI[j + 128];
    float x2r = sR[j + 256], x2i = sI[j + 256];
    float x3r = sR[j + 384], x3i = sI[j + 384];
    int tb = k << SH;
    float c1 = twr[tb], s1 = twi[tb];
    if (INV) s1 = -s1;
    float c2 = c1 * c1 - s1 * s1, s2 = 2.f * c1 * s1;
    float c3 = c1 * c2 - s1 * s2, s3 = c1 * s2 + s1 * c2;
    float a1r = x1r * c1 - x1i * s1, a1i = x1r * s1 + x1i * c1;
    float a2r = x2r * c2 - x2i * s2, a2i = x2r * s2 + x2i * c2;
    float a3r = x3r * c3 - x3i * s3, a3i = x3r * s3 + x3i * c3;
    float t0r = x0r + a2r, t0i = x0i + a2i;
    float t1r = x0r - a2r, t1i = x0i - a2i;
    float t2r = a1r + a3r, t2i = a1i + a3i;
    float t3r = a1r - a3r, t3i = a1i - a3i;
    float i3r = INV ? -t3i : t3i;
    float i3i = INV ?  t3r : -t3r;
    dR[d0]         = t0r + t2r;  dI[d0]         = t0i + t2i;
    dR[d0 + P]     = t1r + i3r;  dI[d0 + P]     = t1i + i3i;
    dR[d0 + 2 * P] = t0r - t2r;  dI[d0 + 2 * P] = t0i - t2i;
    dR[d0 + 3 * P] = t1r - i3r;  dI[d0 + 3 * P] = t1i - i3i;
}

// ================= k_init (round-7 verified, unchanged) ======================
struct __align__(16) SMemI {
    float xb[NFFT];
    float C0r[NH], C0i[NH];
    float C1r[NH], C1i[NH];
    float win[NFFT];
    float twr[256], twi[256];
    float mag[516];
};

extern "C" __global__ __launch_bounds__(NT)
void k_init(const float* __restrict__ mel,
            const float* __restrict__ invmel,
            float* __restrict__ ws) {
    __shared__ SMemI sm;
    const int tid = threadIdx.x;
    const int t   = blockIdx.x;

    for (int n = tid; n < NFFT; n += NT) {
        double a = (2.0 * 3.14159265358979323846) * (double)n / 1024.0;
        sm.win[n] = (float)(0.5 - 0.5 * cos(a));
    }
    for (int j = tid; j < 256; j += NT) {
        double a = (2.0 * 3.14159265358979323846) * (double)j / 512.0;
        sm.twr[j] = (float)cos(a);
        sm.twi[j] = (float)(-sin(a));
    }
    __syncthreads();
    if (t == 0) {
        for (int n = tid; n < NFFT; n += NT) ws[TBL_WIN + n] = sm.win[n];
        for (int j = tid; j < 256; j += NT) {
            ws[TBL_TWR + j] = sm.twr[j];
            ws[TBL_TWI + j] = sm.twi[j];
        }
        for (int k = tid; k < NBINS; k += NT) {
            double a = (2.0 * 3.14159265358979323846) * (double)k / 1024.0;
            ws[TBL_W1R + k] = (float)cos(a);
            ws[TBL_W1I + k] = (float)sin(a);
        }
        ((int*)ws)[BAR_SLOT + tid]       = 0;
        ((int*)ws)[BAR_SLOT + 256 + tid] = 0;
        if (tid == 0) ((int*)ws)[BAR_GEN] = 0;
    }

    for (int p = t * NT + tid; p < SIGLEN; p += NFR * NT) {
        int tq = p >> 6, io = p & 63;
        float s = 0.f;
#pragma unroll
        for (int m = 0; m < 16; ++m) {
            int tp = tq - m;
            if (tp >= 0 && tp < NFR) {
                float w = sm.win[io + (m << 6)];
                s += w * w;
            }
        }
        ws[OFF_IWS + p] = (s > 1e-11f) ? (1.0f / s) : 1.0f;
    }

    if (tid < NMELS) sm.xb[tid] = exp10f(mel[tid * NFR + t]);
    __syncthreads();
    for (int k = tid; k < NBINS; k += NT) {
        const float* row = invmel + k * NMELS;
        float s = 0.f;
#pragma unroll 8
        for (int j = 0; j < NMELS; ++j) s += row[j] * sm.xb[j];
        ws[OFF_MAG + t * NBINS + k] = s;
        sm.mag[k] = s;
    }
    __syncthreads();

    for (int k = tid; k < NH; k += NT) {
        float xr = sm.mag[k], yr = sm.mag[512 - k];
        double a = (2.0 * 3.14159265358979323846) * (double)k / 1024.0;
        float c = (float)cos(a), s = (float)sin(a);
        float dr = xr - yr;
        sm.C1r[k] = ((xr + yr) - s * dr) * (1.0f / 1024.0f);
        sm.C1i[k] = (c * dr) * (1.0f / 1024.0f);
    }
    __syncthreads();
    if (tid < 128) {
        float x0r = sm.C1r[tid],       x0i = sm.C1i[tid];
        float x1r = sm.C1r[tid + 128], x1i = sm.C1i[tid + 128];
        float x2r = sm.C1r[tid + 256], x2i = sm.C1i[tid + 256];
        float x3r = sm.C1r[tid + 384], x3i = sm.C1i[tid + 384];
        float t0r = x0r + x2r, t0i = x0i + x2i;
        float t1r = x0r - x2r, t1i = x0i - x2i;
        float t2r = x1r + x3r, t2i = x1i + x3i;
        float t3r = x1r - x3r, t3i = x1i - x3i;
        float4 vr = make_float4(t0r + t2r, t1r - t3i, t0r - t2r, t1r + t3i);
        float4 vi = make_float4(t0i + t2i, t1i + t3r, t0i - t2i, t1i - t3r);
        ((float4*)sm.C0r)[tid] = vr;
        ((float4*)sm.C0i)[tid] = vi;
    }
    __syncthreads();
    if (tid < 128) r4b<4, 5, true>(sm.C0r, sm.C0i, sm.C1r, sm.C1i, sm.twr, sm.twi, tid);
    __syncthreads();
    if (tid < 128) r4b<16, 3, true>(sm.C1r, sm.C1i, sm.C0r, sm.C0i, sm.twr, sm.twi, tid);
    __syncthreads();
    if (tid < 128) r4b<64, 1, true>(sm.C0r, sm.C0i, sm.C1r, sm.C1i, sm.twr, sm.twi, tid);
    __syncthreads();
    {
        float c = sm.twr[tid], s = -sm.twi[tid];
        float x0r = sm.C1r[tid], x0i = sm.C1i[tid];
        float x1r = sm.C1r[tid + 256], x1i = sm.C1i[tid + 256];
        float ar = x1r * c - x1i * s, ai = x1r * s + x1i * c;
        sm.C0r[tid]       = x0r + ar;  sm.C0i[tid]       = x0i + ai;
        sm.C0r[tid + 256] = x0r - ar;  sm.C0i[tid + 256] = x0i - ai;
    }
    __syncthreads();

    float4 w4 = ((float4*)sm.win)[tid];
    float4 o;
    o.x = w4.x * sm.C0r[2 * tid];
    o.y = w4.y * sm.C0i[2 * tid];
    o.z = w4.z * sm.C0r[2 * tid + 1];
    o.w = w4.w * sm.C0i[2 * tid + 1];
    *(float4*)&ws[OFF_F + (t << 10) + (tid << 2)] = o;
}

// ============== persistent Griffin-Lim ======================================
struct __align__(16) SM1 {
    float C0r[NH], C0i[NH];
    float C1r[NH], C1i[NH];
    float twr[256], twi[256];
};

// two-hop global barrier (round-7 proven); block0 gathers with 256 threads,
// both slot loads issued before checking (parallel round-trips).
__device__ __forceinline__ void gbar(int* bar, int t, int tid, int bc) {
    __syncthreads();   // block work done; vmcnt drained -> sc1 stores at L3
    if (tid == 0)
        __hip_atomic_store(bar + BAR_SLOT + t, bc,
                           __ATOMIC_RELAXED, __HIP_MEMORY_SCOPE_AGENT);
    if (t == 0) {
        const int* f0 = bar + BAR_SLOT + tid;
        const int* f1 = bar + BAR_SLOT + 256 + tid;
        for (;;) {
            int a = __hip_atomic_load(f0, __ATOMIC_RELAXED, __HIP_MEMORY_SCOPE_AGENT);
            int b = __hip_atomic_load(f1, __ATOMIC_RELAXED, __HIP_MEMORY_SCOPE_AGENT);
            if (a >= bc && b >= bc) break;
            __builtin_amdgcn_s_sleep(1);
        }
        __syncthreads();
        if (tid == 0)
            __hip_atomic_store(bar + BAR_GEN, bc,
                               __ATOMIC_RELAXED, __HIP_MEMORY_SCOPE_AGENT);
    }
    if (tid == 0) {
        while (__hip_atomic_load(bar + BAR_GEN,
                                 __ATOMIC_RELAXED, __HIP_MEMORY_SCOPE_AGENT) < bc)
            __builtin_amdgcn_s_sleep(2);
    }
    __syncthreads();
}

extern "C" __global__ __launch_bounds__(NT)
void k_persist(float* __restrict__ ws, float* __restrict__ out) {
    __shared__ SM1 sm;
    const int tid = threadIdx.x;
    const int t   = blockIdx.x;       // frame owned
    const int j2  = 512 - tid;

    const float* tbl  = ws;
    const float* magg = ws + OFF_MAG;
    const float* iws  = ws + OFF_IWS;
    float* F  = ws + OFF_F;
    float* X  = ws + OFF_X;
    int*   bar = (int*)ws;

    // ---- one-time staging ----
    if (tid < 64)       ((float4*)sm.twr)[tid]      = ((const float4*)(tbl + TBL_TWR))[tid];
    else if (tid < 128) ((float4*)sm.twi)[tid - 64] = ((const float4*)(tbl + TBL_TWI))[tid - 64];

    // window register pairs
    const float2* winp = (const float2*)(tbl + TBL_WIN);
    float2 wa = winp[tid];         // win[2tid], win[2tid+1]
    float2 wb = winp[tid + 256];   // win[2tid+512], win[2tid+513]
    float2 wz0 = make_float2(0.f, 0.f), wz1 = wz0, wz2 = wz0, wz3 = wz0;
    if (tid < 128) {
        wz0 = winp[tid];
        wz1 = winp[tid + 128];
        wz2 = winp[tid + 256];
        wz3 = winp[tid + 384];
    }

    float m_a, m_b, m_ny = 0.f, w1r_a, w1i_a, w1r_b, w1i_b;
    {
        const int s0 = t * NBINS;
        if (tid == 0) {
            m_a = magg[s0]; m_ny = magg[s0 + 512]; m_b = magg[s0 + 256];
            w1r_a = 1.f; w1i_a = 0.f; w1r_b = 0.f; w1i_b = 1.f;
        } else {
            m_a = magg[s0 + tid]; m_b = magg[s0 + j2];
            w1r_a = tbl[TBL_W1R + tid]; w1i_a = tbl[TBL_W1I + tid];
            w1r_b = tbl[TBL_W1R + j2];  w1i_b = tbl[TBL_W1I + j2];
        }
    }
    // segment ownership: seg t (lanes 0..63); blocks >=497 also seg t+15 (lanes 64..127)
    const bool extra = (t >= 497);
    int gseg = -1;
    if (tid < 64) gseg = t;
    else if (tid < 128 && extra) gseg = t + 15;
    const int u = tid & 63;
    float iwreg = 0.f;
    if (gseg >= 0) iwreg = iws[(gseg << 6) + u];

    // ---- prologue: x^0 segment(s) from k_init frames ----
    if (gseg >= 0) {
        float acc = 0.f;
#pragma unroll
        for (int m = 0; m < 16; ++m) {
            int tp = gseg - m;
            if (tp >= 0 && tp < NFR)
                acc += coh_load1(&F[(tp << 10) + u + (m << 6)]);
        }
        coh_store1(&X[(gseg << 6) + u], acc * iwreg);
    }
    gbar(bar, t, tid, 1);

    int bc = 2;
#pragma unroll 1
    for (int it = 1; it <= NITER; ++it) {
        // ===== phase A =====
        // fused: coherent X load + window + fwd radix-4 stage0 -> C0
        if (tid < 128) {
            const float* xp = X + (t << 6) + (tid << 1);
            float2 z0 = coh_load2(xp);
            float2 z1 = coh_load2(xp + 256);
            float2 z2 = coh_load2(xp + 512);
            float2 z3 = coh_load2(xp + 768);
            float x0r = z0.x * wz0.x, x0i = z0.y * wz0.y;
            float x1r = z1.x * wz1.x, x1i = z1.y * wz1.y;
            float x2r = z2.x * wz2.x, x2i = z2.y * wz2.y;
            float x3r = z3.x * wz3.x, x3i = z3.y * wz3.y;
            float t0r = x0r + x2r, t0i = x0i + x2i;
            float t1r = x0r - x2r, t1i = x0i - x2i;
            float t2r = x1r + x3r, t2i = x1i + x3i;
            float t3r = x1r - x3r, t3i = x1i - x3i;
            float4 vr = make_float4(t0r + t2r, t1r + t3i, t0r - t2r, t1r - t3i);
            float4 vi = make_float4(t0i + t2i, t1i - t3r, t0i - t2i, t1i + t3r);
            ((float4*)sm.C0r)[tid] = vr;
            ((float4*)sm.C0i)[tid] = vi;
        }
        __syncthreads();
        if (tid < 128) r4b<4, 5, false>(sm.C0r, sm.C0i, sm.C1r, sm.C1i, sm.twr, sm.twi, tid);
        __syncthreads();
        if (tid < 128) r4b<16, 3, false>(sm.C1r, sm.C1i, sm.C0r, sm.C0i, sm.twr, sm.twi, tid);
        __syncthreads();
        if (tid < 128) r4b<64, 1, false>(sm.C0r, sm.C0i, sm.C1r, sm.C1i, sm.twr, sm.twi, tid);
        __syncthreads();

        // ===== fused fwd final radix-2 + unpack + phase projection -> C0 =====
        // (bit-identical to r2-then-project; per-thread recompute of its 2 butterflies)
        if (tid == 0) {
            float zr0 = sm.C1r[0] + sm.C1r[256], zi0 = sm.C1i[0] + sm.C1i[256]; // Z[0]
            float z6r = sm.C1r[0] - sm.C1r[256], z6i = sm.C1i[0] - sm.C1i[256]; // Z[256]
            float e0 = zr0 + zi0;
            float e5 = zr0 - zi0;
            float X0 = m_a  * e0 / fmaxf(1e-8f, fabsf(e0));
            float X5 = m_ny * e5 / fmaxf(1e-8f, fabsf(e5));
            sm.C0r[0] = (X0 + X5) * (1.0f / 1024.0f);
            sm.C0i[0] = (X0 - X5) * (1.0f / 1024.0f);
            float sc6 = m_b / fmaxf(1e-8f, sqrtf(z6r * z6r + z6i * z6i));
            float X6r = z6r * sc6, X6i = -z6i * sc6;
            sm.C0r[256] = X6r * (2.0f / 1024.0f);
            sm.C0i[256] = -X6i * (2.0f / 1024.0f);
        } else {
            const int k2 = 256 - tid;
            // Z[tid] (first output of butterfly k=tid)
            float c1 = sm.twr[tid], s1 = sm.twi[tid];
            float y1r = sm.C1r[tid + 256], y1i = sm.C1i[tid + 256];
            float a1r = y1r * c1 - y1i * s1, a1i = y1r * s1 + y1i * c1;
            float zr = sm.C1r[tid] + a1r, zi = sm.C1i[tid] + a1i;
            // Z[512-tid] (second output of butterfly k=256-tid)
            float c2 = sm.twr[k2], s2 = sm.twi[k2];
            float y2r = sm.C1r[k2 + 256], y2i = sm.C1i[k2 + 256];
            float b1r = y2r * c2 - y2i * s2, b1i = y2r * s2 + y2i * c2;
            float ur = sm.C1r[k2] - b1r, ui = sm.C1i[k2] - b1i;
            // projection (verbatim round-7 math)
            float er = 0.5f * (zr + ur), ei = 0.5f * (zi - ui);
            float dr = zr - ur,          di = zi + ui;
            float odr = 0.5f * di, odi = -0.5f * dr;
            float e1r = er + w1r_a * odr + w1i_a * odi;
            float e1i = ei + w1r_a * odi - w1i_a * odr;
            float e2r =  er + w1r_b * odr - w1i_b * odi;
            float e2i = -ei - w1r_b * odi - w1i_b * odr;
            float sc1 = m_a / fmaxf(1e-8f, sqrtf(e1r * e1r + e1i * e1i));
            float sc2 = m_b / fmaxf(1e-8f, sqrtf(e2r * e2r + e2i * e2i));
            float X1r = e1r * sc1, X1i = e1i * sc1;
            float X2r = e2r * sc2, X2i = e2i * sc2;
            float Er = X1r + X2r, Ei = X1i - X2i;
            float Dr = X1r - X2r, Di = X1i + X2i;
            float wdr = w1r_a * Dr - w1i_a * Di, wdi = w1r_a * Di + w1i_a * Dr;
            sm.C0r[tid] = (Er - wdi) * (1.0f / 1024.0f);
            sm.C0i[tid] = (Ei + wdr) * (1.0f / 1024.0f);
            float wdr2 = -w1r_b * Dr - w1i_b * Di, wdi2 = w1r_b * Di - w1i_b * Dr;
            sm.C0r[j2] = (Er - wdi2) * (1.0f / 1024.0f);
            sm.C0i[j2] = (-Ei + wdr2) * (1.0f / 1024.0f);
        }
        __syncthreads();

        // inverse FFT: A in C0 -> stage0 -> C1 -> ... -> C0
        if (tid < 128) {
            float x0r = sm.C0r[tid],       x0i = sm.C0i[tid];
            float x1r = sm.C0r[tid + 128], x1i = sm.C0i[tid + 128];
            float x2r = sm.C0r[tid + 256], x2i = sm.C0i[tid + 256];
            float x3r = sm.C0r[tid + 384], x3i = sm.C0i[tid + 384];
            float t0r = x0r + x2r, t0i = x0i + x2i;
            float t1r = x0r - x2r, t1i = x0i - x2i;
            float t2r = x1r + x3r, t2i = x1i + x3i;
            float t3r = x1r - x3r, t3i = x1i - x3i;
            float4 vr = make_float4(t0r + t2r, t1r - t3i, t0r - t2r, t1r + t3i);
            float4 vi = make_float4(t0i + t2i, t1i + t3r, t0i - t2i, t1i - t3r);
            ((float4*)sm.C1r)[tid] = vr;
            ((float4*)sm.C1i)[tid] = vi;
        }
        __syncthreads();
        if (tid < 128) r4b<4, 5, true>(sm.C1r, sm.C1i, sm.C0r, sm.C0i, sm.twr, sm.twi, tid);
        __syncthreads();
        if (tid < 128) r4b<16, 3, true>(sm.C0r, sm.C0i, sm.C1r, sm.C1i, sm.twr, sm.twi, tid);
        __syncthreads();
        if (tid < 128) r4b<64, 1, true>(sm.C1r, sm.C1i, sm.C0r, sm.C0i, sm.twr, sm.twi, tid);
        __syncthreads();
        {   // fused inv final radix-2 + window + coherent frame store (reads C0)
            float c = sm.twr[tid], s = -sm.twi[tid];
            float x0r = sm.C0r[tid], x0i = sm.C0i[tid];
            float x1r = sm.C0r[tid + 256], x1i = sm.C0i[tid + 256];
            float ar = x1r * c - x1i * s, ai = x1r * s + x1i * c;
            float y0r = x0r + ar, y0i = x0i + ai;   // frame[2tid], frame[2tid+1]
            float y1r = x0r - ar, y1i = x0i - ai;   // frame[2tid+512], frame[2tid+513]
            coh_store2(&F[(t << 10) + (tid << 1)],
                       make_float2(wa.x * y0r, wa.y * y0i));
            coh_store2(&F[(t << 10) + 512 + (tid << 1)],
                       make_float2(wb.x * y1r, wb.y * y1i));
        }
        gbar(bar, t, tid, bc++);   // F^{it} complete everywhere

        // ===== phase B: OLA own segment(s) =====
        if (gseg >= 0) {
            float acc = 0.f;
#pragma unroll
            for (int m = 0; m < 16; ++m) {
                int tp = gseg - m;
                if (tp >= 0 && tp < NFR)
                    acc += coh_load1(&F[(tp << 10) + u + (m << 6)]);
            }
            float val = acc * iwreg;
            if (it < NITER) coh_store1(&X[(gseg << 6) + u], val);
            else            out[(gseg << 6) + u] = val;
        }
        if (it < NITER)
            gbar(bar, t, tid, bc++);   // x^{it} complete everywhere
    }
}

extern "C" void kernel_launch(void* const* d_in, const int* in_sizes, int n_in,
                              void* d_out, int out_size, void* d_ws, size_t ws_size,
                              hipStream_t stream) {
    const float* mel    = (const float*)d_in[0];
    const float* invmel = (const float*)d_in[1];
    float* out = (float*)d_out;
    float* ws  = (float*)d_ws;

    k_init<<<NFR, NT, 0, stream>>>(mel, invmel, ws);
    k_persist<<<NB, NT, 0, stream>>>(ws, out);
}